// Round 1
// baseline (77.406 us; speedup 1.0000x reference)
//
#include <hip/hip_runtime.h>

#define NBLK 2048
#define NTHR 256

// Kernel 1: fused 4-way dot-product partial reduction.
// input  : (N, 2) fp32 row-major (interleaved columns)
// weight : (4, N) fp32 row-major
// out[0]=w0.in[:,0]  out[1]=w1.in[:,0]  out[2]=w2.in[:,1]  out[3]=w3.in[:,1]
__global__ __launch_bounds__(NTHR) void motor_partial(
    const float* __restrict__ inp,
    const float* __restrict__ w,
    float* __restrict__ partial,
    int n)  // n = IN_FEATURES
{
    const float4* __restrict__ in4 = (const float4*)inp;  // each float4 = 2 rows x 2 cols
    const float4* __restrict__ w0 = (const float4*)(w);
    const float4* __restrict__ w1 = (const float4*)(w + (size_t)n);
    const float4* __restrict__ w2 = (const float4*)(w + 2 * (size_t)n);
    const float4* __restrict__ w3 = (const float4*)(w + 3 * (size_t)n);

    float a0 = 0.f, a1 = 0.f, a2 = 0.f, a3 = 0.f;
    const int n4 = n >> 2;                      // float4 count per weight row
    const int stride = gridDim.x * blockDim.x;

    for (int i = blockIdx.x * NTHR + threadIdx.x; i < n4; i += stride) {
        // covers input rows 4i .. 4i+3
        float4 wa = w0[i];
        float4 wb = w1[i];
        float4 wc = w2[i];
        float4 wd = w3[i];
        float4 p = in4[2 * i];       // rows 4i,4i+1 : (c0,c1,c0,c1)
        float4 q = in4[2 * i + 1];   // rows 4i+2,4i+3

        a0 += wa.x * p.x + wa.y * p.z + wa.z * q.x + wa.w * q.z;
        a1 += wb.x * p.x + wb.y * p.z + wb.z * q.x + wb.w * q.z;
        a2 += wc.x * p.y + wc.y * p.w + wc.z * q.y + wc.w * q.w;
        a3 += wd.x * p.y + wd.y * p.w + wd.z * q.y + wd.w * q.w;
    }

    // wave64 butterfly reduce
    for (int off = 32; off > 0; off >>= 1) {
        a0 += __shfl_down(a0, off);
        a1 += __shfl_down(a1, off);
        a2 += __shfl_down(a2, off);
        a3 += __shfl_down(a3, off);
    }

    __shared__ float s[NTHR / 64][4];
    const int wave = threadIdx.x >> 6;
    if ((threadIdx.x & 63) == 0) {
        s[wave][0] = a0; s[wave][1] = a1; s[wave][2] = a2; s[wave][3] = a3;
    }
    __syncthreads();
    if (threadIdx.x == 0) {
        float r0 = 0.f, r1 = 0.f, r2 = 0.f, r3 = 0.f;
        for (int wv = 0; wv < NTHR / 64; ++wv) {
            r0 += s[wv][0]; r1 += s[wv][1]; r2 += s[wv][2]; r3 += s[wv][3];
        }
        float4* p4 = (float4*)(partial + 4 * (size_t)blockIdx.x);
        *p4 = make_float4(r0, r1, r2, r3);
    }
}

// Kernel 2: deterministic fixed-order final reduce of NBLK x 4 partials.
__global__ __launch_bounds__(NTHR) void motor_finalize(
    const float* __restrict__ partial,
    float* __restrict__ out,
    int nblk)
{
    float a0 = 0.f, a1 = 0.f, a2 = 0.f, a3 = 0.f;
    for (int b = threadIdx.x; b < nblk; b += NTHR) {
        const float4 v = *(const float4*)(partial + 4 * (size_t)b);
        a0 += v.x; a1 += v.y; a2 += v.z; a3 += v.w;
    }
    for (int off = 32; off > 0; off >>= 1) {
        a0 += __shfl_down(a0, off);
        a1 += __shfl_down(a1, off);
        a2 += __shfl_down(a2, off);
        a3 += __shfl_down(a3, off);
    }
    __shared__ float s[NTHR / 64][4];
    const int wave = threadIdx.x >> 6;
    if ((threadIdx.x & 63) == 0) {
        s[wave][0] = a0; s[wave][1] = a1; s[wave][2] = a2; s[wave][3] = a3;
    }
    __syncthreads();
    if (threadIdx.x == 0) {
        float r0 = 0.f, r1 = 0.f, r2 = 0.f, r3 = 0.f;
        for (int wv = 0; wv < NTHR / 64; ++wv) {
            r0 += s[wv][0]; r1 += s[wv][1]; r2 += s[wv][2]; r3 += s[wv][3];
        }
        out[0] = r0; out[1] = r1; out[2] = r2; out[3] = r3;
    }
}

extern "C" void kernel_launch(void* const* d_in, const int* in_sizes, int n_in,
                              void* d_out, int out_size, void* d_ws, size_t ws_size,
                              hipStream_t stream) {
    const float* inp = (const float*)d_in[0];   // (N,2) fp32
    const float* w   = (const float*)d_in[1];   // (4,N) fp32
    float* out = (float*)d_out;
    float* partial = (float*)d_ws;              // NBLK*4 floats = 32 KB

    const int n = in_sizes[0] / 2;              // IN_FEATURES

    motor_partial<<<NBLK, NTHR, 0, stream>>>(inp, w, partial, n);
    motor_finalize<<<1, NTHR, 0, stream>>>(partial, out, NBLK);
}

// Round 2
// 68.444 us; speedup vs baseline: 1.1309x; 1.1309x over previous
//
#include <hip/hip_runtime.h>

#define NBLK 2048
#define NTHR 256

typedef float f32x4 __attribute__((ext_vector_type(4)));

// Kernel 1: fused 4-way dot-product partial reduction.
// input  : (N, 2) fp32 row-major (interleaved columns)
// weight : (4, N) fp32 row-major
// out[0]=w0.in[:,0]  out[1]=w1.in[:,0]  out[2]=w2.in[:,1]  out[3]=w3.in[:,1]
__global__ __launch_bounds__(NTHR) void motor_partial(
    const float* __restrict__ inp,
    const float* __restrict__ w,
    float* __restrict__ partial,
    int n)  // n = IN_FEATURES
{
    const f32x4* __restrict__ in4 = (const f32x4*)inp;  // each f32x4 = 2 rows x 2 cols
    const f32x4* __restrict__ w0 = (const f32x4*)(w);
    const f32x4* __restrict__ w1 = (const f32x4*)(w + (size_t)n);
    const f32x4* __restrict__ w2 = (const f32x4*)(w + 2 * (size_t)n);
    const f32x4* __restrict__ w3 = (const f32x4*)(w + 3 * (size_t)n);

    float a0 = 0.f, a1 = 0.f, a2 = 0.f, a3 = 0.f;
    const int n4 = n >> 2;                      // f32x4 count per weight row
    const int stride = gridDim.x * blockDim.x;

    for (int i = blockIdx.x * NTHR + threadIdx.x; i < n4; i += stride) {
        // weight streams: pure single-use, each 64B line fully consumed by one
        // instruction's lanes -> non-temporal (evict-first) is free BW hygiene.
        f32x4 wa = __builtin_nontemporal_load(w0 + i);
        f32x4 wb = __builtin_nontemporal_load(w1 + i);
        f32x4 wc = __builtin_nontemporal_load(w2 + i);
        f32x4 wd = __builtin_nontemporal_load(w3 + i);
        // input stream: two instructions share each 64B line -> keep cached loads.
        f32x4 p = in4[2 * i];       // rows 4i,4i+1 : (c0,c1,c0,c1)
        f32x4 q = in4[2 * i + 1];   // rows 4i+2,4i+3

        a0 += wa.x * p.x + wa.y * p.z + wa.z * q.x + wa.w * q.z;
        a1 += wb.x * p.x + wb.y * p.z + wb.z * q.x + wb.w * q.z;
        a2 += wc.x * p.y + wc.y * p.w + wc.z * q.y + wc.w * q.w;
        a3 += wd.x * p.y + wd.y * p.w + wd.z * q.y + wd.w * q.w;
    }

    // wave64 butterfly reduce
    for (int off = 32; off > 0; off >>= 1) {
        a0 += __shfl_down(a0, off);
        a1 += __shfl_down(a1, off);
        a2 += __shfl_down(a2, off);
        a3 += __shfl_down(a3, off);
    }

    __shared__ float s[NTHR / 64][4];
    const int wave = threadIdx.x >> 6;
    if ((threadIdx.x & 63) == 0) {
        s[wave][0] = a0; s[wave][1] = a1; s[wave][2] = a2; s[wave][3] = a3;
    }
    __syncthreads();
    if (threadIdx.x == 0) {
        float r0 = 0.f, r1 = 0.f, r2 = 0.f, r3 = 0.f;
        for (int wv = 0; wv < NTHR / 64; ++wv) {
            r0 += s[wv][0]; r1 += s[wv][1]; r2 += s[wv][2]; r3 += s[wv][3];
        }
        float4* p4 = (float4*)(partial + 4 * (size_t)blockIdx.x);
        *p4 = make_float4(r0, r1, r2, r3);
    }
}

// Kernel 2: deterministic fixed-order final reduce of NBLK x 4 partials.
__global__ __launch_bounds__(NTHR) void motor_finalize(
    const float* __restrict__ partial,
    float* __restrict__ out,
    int nblk)
{
    float a0 = 0.f, a1 = 0.f, a2 = 0.f, a3 = 0.f;
    for (int b = threadIdx.x; b < nblk; b += NTHR) {
        const float4 v = *(const float4*)(partial + 4 * (size_t)b);
        a0 += v.x; a1 += v.y; a2 += v.z; a3 += v.w;
    }
    for (int off = 32; off > 0; off >>= 1) {
        a0 += __shfl_down(a0, off);
        a1 += __shfl_down(a1, off);
        a2 += __shfl_down(a2, off);
        a3 += __shfl_down(a3, off);
    }
    __shared__ float s[NTHR / 64][4];
    const int wave = threadIdx.x >> 6;
    if ((threadIdx.x & 63) == 0) {
        s[wave][0] = a0; s[wave][1] = a1; s[wave][2] = a2; s[wave][3] = a3;
    }
    __syncthreads();
    if (threadIdx.x == 0) {
        float r0 = 0.f, r1 = 0.f, r2 = 0.f, r3 = 0.f;
        for (int wv = 0; wv < NTHR / 64; ++wv) {
            r0 += s[wv][0]; r1 += s[wv][1]; r2 += s[wv][2]; r3 += s[wv][3];
        }
        out[0] = r0; out[1] = r1; out[2] = r2; out[3] = r3;
    }
}

extern "C" void kernel_launch(void* const* d_in, const int* in_sizes, int n_in,
                              void* d_out, int out_size, void* d_ws, size_t ws_size,
                              hipStream_t stream) {
    const float* inp = (const float*)d_in[0];   // (N,2) fp32
    const float* w   = (const float*)d_in[1];   // (4,N) fp32
    float* out = (float*)d_out;
    float* partial = (float*)d_ws;              // NBLK*4 floats = 32 KB

    const int n = in_sizes[0] / 2;              // IN_FEATURES

    motor_partial<<<NBLK, NTHR, 0, stream>>>(inp, w, partial, n);
    motor_finalize<<<1, NTHR, 0, stream>>>(partial, out, NBLK);
}